// Round 10
// baseline (258.180 us; speedup 1.0000x reference)
//
#include <hip/hip_runtime.h>

#define DDIM    128
#define NNODES  50000
#define NEDGES  800000
#define NLAYERS 3
#define LN_EPS  1e-5f
#define CAP     64                                            // max in-degree; Poisson(16): P(deg>64)~5e-19*50K — safe. 64*2B = 128B-aligned ushort rows
#define NSLICE  8
#define SLICESZ ((NNODES + NSLICE - 1) / NSLICE)              // 6250
#define FILL_EPT 8
#define FILL_CHUNK (256 * FILL_EPT)                           // 2048
#define FILL_NCHUNK ((NEDGES + FILL_CHUNK - 1) / FILL_CHUNK)  // 391

#define FILLB  (FILL_NCHUNK * NSLICE)                         // 3128 (sliced: write locality — R2 45us vs R3 53 vs R4 72)
#define PAIRB  (2 * FILLB)                                    // 6256: even=fill, odd=embed (R7 interleave, best)
#define WPACKB ((NLAYERS * 4096 + 255) / 256)                 // 48 (tail blocks)

typedef short s16x8 __attribute__((ext_vector_type(8)));
typedef float f32x4 __attribute__((ext_vector_type(4)));
typedef unsigned int u32;

__device__ __forceinline__ unsigned short f2bf(float f) {
    union { float f; unsigned u; } c; c.f = f;
    unsigned r = c.u + 0x7fff + ((c.u >> 16) & 1);   // RNE
    return (unsigned short)(r >> 16);
}
__device__ __forceinline__ float bf2f_u(unsigned short h) {
    union { unsigned u; float f; } c; c.u = (unsigned)h << 16;
    return c.f;
}
__device__ __forceinline__ float bflo(u32 v) { return __uint_as_float(v << 16); }
__device__ __forceinline__ float bfhi(u32 v) { return __uint_as_float(v & 0xffff0000u); }

// ---------------------------------------------------------------------------
// PREP: fill + embed INTERLEAVED by block parity (R7-proven best).
// R10: srcs stored as USHORT (ids < 50K), CAP 64 -> scattered srcs
// write-back volume halves; values bit-identical (absmax must stay 0.0625).
// R8 lesson: do NOT merge with the layer kernel (occupancy context).
// ---------------------------------------------------------------------------
__global__ __launch_bounds__(256) void prep_kernel(
    const int* __restrict__ edge,
    int* __restrict__ cursor, unsigned short* __restrict__ srcs,
    const float* __restrict__ Wl, const float* __restrict__ Wr,
    unsigned short* __restrict__ wpk,
    const float* __restrict__ node_emb, const int* __restrict__ pos,
    const float* __restrict__ pos_table,
    const float* __restrict__ eg, const float* __restrict__ eb,
    uint4* __restrict__ xh4)
{
    int t = threadIdx.x;
    int bid = blockIdx.x;

    if (bid < PAIRB && (bid & 1) == 0) {
        // ---- fill: fi -> dst slice (fi&7), edge chunk (fi>>3) ----
        int fi = bid >> 1;
        int slice = fi & (NSLICE - 1);
        int chunk = fi >> 3;
        int lo = slice * SLICESZ;
        int hi = lo + SLICESZ;
        int base = chunk * FILL_CHUNK + t * FILL_EPT;   // NEDGES % 8 == 0
        if (base < NEDGES) {
            int4 d0 = *(const int4*)(edge + NEDGES + base);
            int4 d1 = *(const int4*)(edge + NEDGES + base + 4);
            int4 s0 = *(const int4*)(edge + base);
            int4 s1 = *(const int4*)(edge + base + 4);
            int dd[8] = {d0.x, d0.y, d0.z, d0.w, d1.x, d1.y, d1.z, d1.w};
            int ss[8] = {s0.x, s0.y, s0.z, s0.w, s1.x, s1.y, s1.z, s1.w};
            #pragma unroll
            for (int i = 0; i < 8; ++i) {
                int d = dd[i];
                if (d >= lo && d < hi) {
                    int slot = atomicAdd(&cursor[d], 1);
                    srcs[d * CAP + slot] = (unsigned short)ss[i];
                }
            }
        }
        return;
    }

    if (bid >= PAIRB) {
        // ---- wpack (tail blocks) ----
        int idx = (bid - PAIRB) * 256 + t;
        if (idx >= NLAYERS * 4096) return;
        int l   = idx >> 12;
        int rem = idx & 4095;
        int kt = rem >> 9, ct = (rem >> 6) & 7, ln = rem & 63;
        int k0 = kt * 32 + ((ln >> 4) << 3);
        int c  = ct * 16 + (ln & 15);
        const float* src = (kt < 4)
            ? Wl + (size_t)l * DDIM * DDIM + (size_t)k0 * DDIM + c
            : Wr + (size_t)l * DDIM * DDIM + (size_t)(k0 - 128) * DDIM + c;
        s16x8 o;
        #pragma unroll
        for (int j = 0; j < 8; ++j) o[j] = (short)f2bf(src[j * DDIM]);
        *(s16x8*)(wpk + (size_t)idx * 8) = o;
        return;
    }

    // ---- embed + LN (odd blocks): wave = 4 nodes ----
    int bi = bid >> 1;                    // [0, 3128); >=3125 guarded below
    int wv = (bi * 256 + t) >> 6;
    int lane = t & 63;
    int h = lane >> 4;
    int L = lane & 15;
    int n = wv * 4 + h;
    if (n >= NNODES) return;

    const float scale = 11.313708498984761f;  // sqrt(128)
    int p = pos[n];

    const float* nb = node_emb + (size_t)n * DDIM + L * 8;
    const float* pb = pos_table + (size_t)p * DDIM + L * 8;
    float4 ne0 = *(const float4*)(nb);
    float4 ne1 = *(const float4*)(nb + 4);
    float4 pt0 = *(const float4*)(pb);
    float4 pt1 = *(const float4*)(pb + 4);

    float v[8];
    v[0] = ne0.x * scale + pt0.x;  v[1] = ne0.y * scale + pt0.y;
    v[2] = ne0.z * scale + pt0.z;  v[3] = ne0.w * scale + pt0.w;
    v[4] = ne1.x * scale + pt1.x;  v[5] = ne1.y * scale + pt1.y;
    v[6] = ne1.z * scale + pt1.z;  v[7] = ne1.w * scale + pt1.w;

    float s = 0.f, s2 = 0.f;
    #pragma unroll
    for (int k = 0; k < 8; ++k) { s += v[k]; s2 += v[k] * v[k]; }
    #pragma unroll
    for (int m = 8; m > 0; m >>= 1) {     // masks <16: stays within 16-group
        s  += __shfl_xor(s,  m, 64);
        s2 += __shfl_xor(s2, m, 64);
    }
    float mean = s * (1.0f / DDIM);
    float var  = s2 * (1.0f / DDIM) - mean * mean;
    float rstd = rsqrtf(var + LN_EPS);

    float4 gv0 = *(const float4*)(eg + L * 8);
    float4 gv1 = *(const float4*)(eg + L * 8 + 4);
    float4 bv0 = *(const float4*)(eb + L * 8);
    float4 bv1 = *(const float4*)(eb + L * 8 + 4);
    float gq[8] = {gv0.x, gv0.y, gv0.z, gv0.w, gv1.x, gv1.y, gv1.z, gv1.w};
    float bq[8] = {bv0.x, bv0.y, bv0.z, bv0.w, bv1.x, bv1.y, bv1.z, bv1.w};

    float y[8];
    #pragma unroll
    for (int k = 0; k < 8; ++k) y[k] = (v[k] - mean) * rstd * gq[k] + bq[k];

    uint4 o;
    o.x = (u32)f2bf(y[0]) | ((u32)f2bf(y[1]) << 16);
    o.y = (u32)f2bf(y[2]) | ((u32)f2bf(y[3]) << 16);
    o.z = (u32)f2bf(y[4]) | ((u32)f2bf(y[5]) << 16);
    o.w = (u32)f2bf(y[6]) | ((u32)f2bf(y[7]) << 16);
    xh4[(size_t)n * 16 + L] = o;
}

// ---------------------------------------------------------------------------
// FUSED layer: gather (16KB XOR-swizzled LDS tile) + MFMA + LN.
// R10: (a) __launch_bounds__(256,5) on the CLEAN R2 body (88 VGPR <= 102
// cap — R5's spill was the bundled +16-VGPR prefetch, not the floor itself).
// LDS 5x32KB = 160KB exact. If allocator was limiting to 4 blk/CU this
// buys +25% waves for the latency-bound gather; if already 5, it's a no-op.
// (b) srcs reads are ushort now. Gather remains service-rate bound
// (~83MB of random 256B reads at ~1.9TB/s); R3/R5/R6 latency levers null.
// ---------------------------------------------------------------------------
__global__ __launch_bounds__(256, 5) void sage_fused_kernel(
    const int* __restrict__ deg,
    const unsigned short* __restrict__ srcs,
    const uint4* __restrict__ xin4,          // bf16 rows, previous layer
    const unsigned short* __restrict__ xin,  // scalar view of same buffer
    const unsigned short* __restrict__ wpk,  // this layer, B-frag order (kt-major)
    const float* __restrict__ bl,
    const float* __restrict__ g,
    const float* __restrict__ b,
    unsigned short* __restrict__ xh_out,     // bf16 out (non-last layers)
    float* __restrict__ xout)                // fp32 out (last layer), else null
{
    __shared__ unsigned short wlds[8192];       // 16 KB: one kt-pair of W frags
    __shared__ uint4 aggl[64 * 16];             // 16 KB agg tile (swizzled)

    int t    = threadIdx.x;
    int wave = t >> 6;
    int lane = t & 63;
    int cl   = lane & 15;
    int q    = lane >> 4;

    // stage pass-0 weights (kt 0,1); loads stay in flight under gather
    {
        const s16x8* srcv = (const s16x8*)wpk;
        s16x8* dstv = (s16x8*)wlds;
        #pragma unroll
        for (int i = 0; i < 4; ++i) dstv[t + i * 256] = srcv[t + i * 256];
    }

    int m0 = blockIdx.x * 64;

    // ---- gather phase: this wave fills rows [wave*16, wave*16+16) ----
    for (int r = 0; r < 4; ++r) {
        int nl = wave * 16 + r * 4 + q;
        int n  = m0 + nl;
        float acc[8];
        #pragma unroll
        for (int k = 0; k < 8; ++k) acc[k] = 0.f;
        if (n < NNODES) {
            int dg  = deg[n];
            int beg = n * CAP;
            for (int j = 0; j < dg; j += 8) {
                int sidx[8];
                #pragma unroll
                for (int c = 0; c < 8; ++c) {
                    int jj = j + c;
                    sidx[c] = (jj < dg) ? (int)srcs[beg + jj] : -1;
                }
                uint4 u[8];
                #pragma unroll
                for (int c = 0; c < 8; ++c) {
                    u[c] = make_uint4(0u, 0u, 0u, 0u);
                    if (sidx[c] >= 0) u[c] = xin4[(size_t)sidx[c] * 16 + cl];
                }
                #pragma unroll
                for (int c = 0; c < 8; ++c) {
                    acc[0] += bflo(u[c].x); acc[1] += bfhi(u[c].x);
                    acc[2] += bflo(u[c].y); acc[3] += bfhi(u[c].y);
                    acc[4] += bflo(u[c].z); acc[5] += bfhi(u[c].z);
                    acc[6] += bflo(u[c].w); acc[7] += bfhi(u[c].w);
                }
            }
        }
        uint4 o;
        o.x = (u32)f2bf(acc[0]) | ((u32)f2bf(acc[1]) << 16);
        o.y = (u32)f2bf(acc[2]) | ((u32)f2bf(acc[3]) << 16);
        o.z = (u32)f2bf(acc[4]) | ((u32)f2bf(acc[5]) << 16);
        o.w = (u32)f2bf(acc[6]) | ((u32)f2bf(acc[7]) << 16);
        aggl[nl * 16 + (cl ^ (nl & 7))] = o;
    }

    int wbase = m0 + wave * 16;
    int mrow  = wave * 16 + cl;
    int m  = wbase + cl;
    int mc = (m < NNODES) ? m : (NNODES - 1);

    // prefetch xin A-frags (kt 4..7) before the barrier (overlaps barrier wait)
    s16x8 af47[4];
    #pragma unroll
    for (int kt = 4; kt < 8; ++kt)
        af47[kt - 4] = *(const s16x8*)(xin + (size_t)mc * DDIM + (kt - 4) * 32 + q * 8);

    __syncthreads();   // covers pass-0 wlds staging + aggl tile

    f32x4 accm[8];
    #pragma unroll
    for (int ct = 0; ct < 8; ++ct) accm[ct] = (f32x4){0.f, 0.f, 0.f, 0.f};

    #pragma unroll
    for (int p = 0; p < 4; ++p) {
        #pragma unroll
        for (int kk = 0; kk < 2; ++kk) {
            int kt = p * 2 + kk;
            s16x8 af;
            if (kt < 4)
                af = *(const s16x8*)&aggl[mrow * 16 + ((kt * 4 + q) ^ (cl & 7))];
            else
                af = af47[kt - 4];
            #pragma unroll
            for (int ct = 0; ct < 8; ++ct) {
                s16x8 bfr = *(const s16x8*)&wlds[((((kk << 3) + ct) << 6) + lane) * 8];
                accm[ct] = __builtin_amdgcn_mfma_f32_16x16x32_bf16(af, bfr, accm[ct], 0, 0, 0);
            }
        }
        __syncthreads();   // all waves done reading pass p
        if (p < 3) {
            const s16x8* srcv = (const s16x8*)(wpk + (size_t)(p + 1) * 8192);
            s16x8* dstv = (s16x8*)wlds;
            #pragma unroll
            for (int i = 0; i < 4; ++i) dstv[t + i * 256] = srcv[t + i * 256];
            __syncthreads();   // pass p+1 staged
        }
    }

    float bias[8], gg[8], bb[8];
    #pragma unroll
    for (int ct = 0; ct < 8; ++ct) {
        int c = ct * 16 + cl;
        bias[ct] = bl[c]; gg[ct] = g[c]; bb[ct] = b[c];
    }

    float hbuf[8][4];
    #pragma unroll
    for (int ct = 0; ct < 8; ++ct) {
        #pragma unroll
        for (int rr = 0; rr < 4; ++rr) {
            int node = wbase + q * 4 + rr;
            int nc   = (node < NNODES) ? node : (NNODES - 1);
            float hv = fmaxf(accm[ct][rr] + bias[ct], 0.0f);
            hbuf[ct][rr] = hv + bf2f_u(xin[(size_t)nc * DDIM + ct * 16 + cl]);
        }
    }

    float s[4], s2[4];
    #pragma unroll
    for (int rr = 0; rr < 4; ++rr) {
        float a0 = 0.f, a1 = 0.f;
        #pragma unroll
        for (int ct = 0; ct < 8; ++ct) {
            a0 += hbuf[ct][rr];
            a1 += hbuf[ct][rr] * hbuf[ct][rr];
        }
        #pragma unroll
        for (int msk = 1; msk < 16; msk <<= 1) {
            a0 += __shfl_xor(a0, msk, 64);
            a1 += __shfl_xor(a1, msk, 64);
        }
        s[rr] = a0; s2[rr] = a1;
    }

    #pragma unroll
    for (int rr = 0; rr < 4; ++rr) {
        int node = wbase + q * 4 + rr;
        if (node >= NNODES) continue;
        float mean = s[rr] * (1.0f / DDIM);
        float var  = s2[rr] * (1.0f / DDIM) - mean * mean;
        float rstd = rsqrtf(var + LN_EPS);
        #pragma unroll
        for (int ct = 0; ct < 8; ++ct) {
            float y = (hbuf[ct][rr] - mean) * rstd * gg[ct] + bb[ct];
            size_t off = (size_t)node * DDIM + ct * 16 + cl;
            if (xout) xout[off]    = y;          // last layer: fp32 only
            else      xh_out[off]  = f2bf(y);
        }
    }
}

// ---------------------------------------------------------------------------
extern "C" void kernel_launch(void* const* d_in, const int* in_sizes, int n_in,
                              void* d_out, int out_size, void* d_ws, size_t ws_size,
                              hipStream_t stream)
{
    const float* node_emb = (const float*)d_in[0];
    const int*   pos      = (const int*)d_in[1];
    const int*   edge     = (const int*)d_in[2];
    const float* pos_tab  = (const float*)d_in[3];
    const float* Wl       = (const float*)d_in[4];
    const float* bl       = (const float*)d_in[5];
    const float* Wr       = (const float*)d_in[6];
    const float* eg       = (const float*)d_in[7];
    const float* eb       = (const float*)d_in[8];
    const float* hg       = (const float*)d_in[9];
    const float* hb       = (const float*)d_in[10];

    // workspace: [xA bf16 12.8M][xB bf16 12.8M][wpk 0.2M][cursor 0.2M][srcs u16 6.4M]
    unsigned short* xA  = (unsigned short*)d_ws;
    unsigned short* xB  = xA + (size_t)NNODES * DDIM;
    unsigned short* wpk = xB + (size_t)NNODES * DDIM;
    int* cursor = (int*)(wpk + (size_t)NLAYERS * 4096 * 8);
    unsigned short* srcs = (unsigned short*)(cursor + NNODES);

    // ---- cursor zero, then fill/embed interleaved + wpack in ONE dispatch ----
    hipMemsetAsync(cursor, 0, NNODES * sizeof(int), stream);
    prep_kernel<<<PAIRB + WPACKB, 256, 0, stream>>>(
        edge, cursor, srcs, Wl, Wr, wpk,
        node_emb, pos, pos_tab, eg, eb, (uint4*)xA);

    // ---- layers: fused gather+MFMA+LN, ping-pong xA/xB ----
    for (int l = 0; l < NLAYERS; ++l) {
        unsigned short* xin = (l & 1) ? xB : xA;
        unsigned short* xo  = (l & 1) ? xA : xB;
        sage_fused_kernel<<<(NNODES + 63) / 64, 256, 0, stream>>>(
            cursor, srcs, (const uint4*)xin, xin,
            wpk + (size_t)l * 4096 * 8,
            bl + (size_t)l * DDIM,
            hg + (size_t)l * DDIM,
            hb + (size_t)l * DDIM,
            xo, (l == NLAYERS - 1) ? (float*)d_out : (float*)nullptr);
    }
}

// Round 11
// 244.421 us; speedup vs baseline: 1.0563x; 1.0563x over previous
//
#include <hip/hip_runtime.h>

#define DDIM    128
#define NNODES  50000
#define NEDGES  800000
#define NLAYERS 3
#define LN_EPS  1e-5f
#define CAP     64                                            // max in-degree; Poisson(16): P(deg>64)*50K ~ 5e-14 — safe
#define NSLICE  8
#define SLICESZ ((NNODES + NSLICE - 1) / NSLICE)              // 6250
#define FILL_EPT 8
#define FILL_CHUNK (256 * FILL_EPT)                           // 2048
#define FILL_NCHUNK ((NEDGES + FILL_CHUNK - 1) / FILL_CHUNK)  // 391

#define FILLB  (FILL_NCHUNK * NSLICE)                         // 3128 (sliced: write locality — R2 45us vs R3 53 vs R4 72)
#define PAIRB  (2 * FILLB)                                    // 6256: even=fill, odd=embed (R7 interleave, best)
#define WPACKB ((NLAYERS * 4096 + 255) / 256)                 // 48 (tail blocks)

typedef short s16x8 __attribute__((ext_vector_type(8)));
typedef float f32x4 __attribute__((ext_vector_type(4)));
typedef unsigned int u32;

__device__ __forceinline__ unsigned short f2bf(float f) {
    union { float f; unsigned u; } c; c.f = f;
    unsigned r = c.u + 0x7fff + ((c.u >> 16) & 1);   // RNE
    return (unsigned short)(r >> 16);
}
__device__ __forceinline__ float bf2f_u(unsigned short h) {
    union { unsigned u; float f; } c; c.u = (unsigned)h << 16;
    return c.f;
}
__device__ __forceinline__ float bflo(u32 v) { return __uint_as_float(v << 16); }
__device__ __forceinline__ float bfhi(u32 v) { return __uint_as_float(v & 0xffff0000u); }

// ---------------------------------------------------------------------------
// PREP: fill + embed INTERLEAVED by block parity (R7-proven best).
// srcs stored as USHORT (ids < 50K), CAP 64 (R10-proven: prep dropped
// below the fused kernels in the profile) — halves scattered write-back.
// R8 lesson: do NOT merge with the layer kernel (occupancy context).
// ---------------------------------------------------------------------------
__global__ __launch_bounds__(256) void prep_kernel(
    const int* __restrict__ edge,
    int* __restrict__ cursor, unsigned short* __restrict__ srcs,
    const float* __restrict__ Wl, const float* __restrict__ Wr,
    unsigned short* __restrict__ wpk,
    const float* __restrict__ node_emb, const int* __restrict__ pos,
    const float* __restrict__ pos_table,
    const float* __restrict__ eg, const float* __restrict__ eb,
    uint4* __restrict__ xh4)
{
    int t = threadIdx.x;
    int bid = blockIdx.x;

    if (bid < PAIRB && (bid & 1) == 0) {
        // ---- fill: fi -> dst slice (fi&7), edge chunk (fi>>3) ----
        int fi = bid >> 1;
        int slice = fi & (NSLICE - 1);
        int chunk = fi >> 3;
        int lo = slice * SLICESZ;
        int hi = lo + SLICESZ;
        int base = chunk * FILL_CHUNK + t * FILL_EPT;   // NEDGES % 8 == 0
        if (base < NEDGES) {
            int4 d0 = *(const int4*)(edge + NEDGES + base);
            int4 d1 = *(const int4*)(edge + NEDGES + base + 4);
            int4 s0 = *(const int4*)(edge + base);
            int4 s1 = *(const int4*)(edge + base + 4);
            int dd[8] = {d0.x, d0.y, d0.z, d0.w, d1.x, d1.y, d1.z, d1.w};
            int ss[8] = {s0.x, s0.y, s0.z, s0.w, s1.x, s1.y, s1.z, s1.w};
            #pragma unroll
            for (int i = 0; i < 8; ++i) {
                int d = dd[i];
                if (d >= lo && d < hi) {
                    int slot = atomicAdd(&cursor[d], 1);
                    srcs[d * CAP + slot] = (unsigned short)ss[i];
                }
            }
        }
        return;
    }

    if (bid >= PAIRB) {
        // ---- wpack (tail blocks) ----
        int idx = (bid - PAIRB) * 256 + t;
        if (idx >= NLAYERS * 4096) return;
        int l   = idx >> 12;
        int rem = idx & 4095;
        int kt = rem >> 9, ct = (rem >> 6) & 7, ln = rem & 63;
        int k0 = kt * 32 + ((ln >> 4) << 3);
        int c  = ct * 16 + (ln & 15);
        const float* src = (kt < 4)
            ? Wl + (size_t)l * DDIM * DDIM + (size_t)k0 * DDIM + c
            : Wr + (size_t)l * DDIM * DDIM + (size_t)(k0 - 128) * DDIM + c;
        s16x8 o;
        #pragma unroll
        for (int j = 0; j < 8; ++j) o[j] = (short)f2bf(src[j * DDIM]);
        *(s16x8*)(wpk + (size_t)idx * 8) = o;
        return;
    }

    // ---- embed + LN (odd blocks): wave = 4 nodes ----
    int bi = bid >> 1;                    // [0, 3128); >=3125 guarded below
    int wv = (bi * 256 + t) >> 6;
    int lane = t & 63;
    int h = lane >> 4;
    int L = lane & 15;
    int n = wv * 4 + h;
    if (n >= NNODES) return;

    const float scale = 11.313708498984761f;  // sqrt(128)
    int p = pos[n];

    const float* nb = node_emb + (size_t)n * DDIM + L * 8;
    const float* pb = pos_table + (size_t)p * DDIM + L * 8;
    float4 ne0 = *(const float4*)(nb);
    float4 ne1 = *(const float4*)(nb + 4);
    float4 pt0 = *(const float4*)(pb);
    float4 pt1 = *(const float4*)(pb + 4);

    float v[8];
    v[0] = ne0.x * scale + pt0.x;  v[1] = ne0.y * scale + pt0.y;
    v[2] = ne0.z * scale + pt0.z;  v[3] = ne0.w * scale + pt0.w;
    v[4] = ne1.x * scale + pt1.x;  v[5] = ne1.y * scale + pt1.y;
    v[6] = ne1.z * scale + pt1.z;  v[7] = ne1.w * scale + pt1.w;

    float s = 0.f, s2 = 0.f;
    #pragma unroll
    for (int k = 0; k < 8; ++k) { s += v[k]; s2 += v[k] * v[k]; }
    #pragma unroll
    for (int m = 8; m > 0; m >>= 1) {     // masks <16: stays within 16-group
        s  += __shfl_xor(s,  m, 64);
        s2 += __shfl_xor(s2, m, 64);
    }
    float mean = s * (1.0f / DDIM);
    float var  = s2 * (1.0f / DDIM) - mean * mean;
    float rstd = rsqrtf(var + LN_EPS);

    float4 gv0 = *(const float4*)(eg + L * 8);
    float4 gv1 = *(const float4*)(eg + L * 8 + 4);
    float4 bv0 = *(const float4*)(eb + L * 8);
    float4 bv1 = *(const float4*)(eb + L * 8 + 4);
    float gq[8] = {gv0.x, gv0.y, gv0.z, gv0.w, gv1.x, gv1.y, gv1.z, gv1.w};
    float bq[8] = {bv0.x, bv0.y, bv0.z, bv0.w, bv1.x, bv1.y, bv1.z, bv1.w};

    float y[8];
    #pragma unroll
    for (int k = 0; k < 8; ++k) y[k] = (v[k] - mean) * rstd * gq[k] + bq[k];

    uint4 o;
    o.x = (u32)f2bf(y[0]) | ((u32)f2bf(y[1]) << 16);
    o.y = (u32)f2bf(y[2]) | ((u32)f2bf(y[3]) << 16);
    o.z = (u32)f2bf(y[4]) | ((u32)f2bf(y[5]) << 16);
    o.w = (u32)f2bf(y[6]) | ((u32)f2bf(y[7]) << 16);
    xh4[(size_t)n * 16 + L] = o;
}

// ---------------------------------------------------------------------------
// FUSED layer: gather (16KB XOR-swizzled LDS tile) + MFMA + LN.
// __launch_bounds__(256,4): TWICE-proven (R5, R10) that any floor >=5 makes
// the allocator emit a 48-VGPR spilling schedule (+8MB scratch, +3us/layer).
// The R2 body needs ~88 VGPR; do not floor above 4. Gather is service-rate
// bound (~83MB of random 256B L2-miss reads at ~2TB/s); R3/R5/R6 latency
// levers all null. R8: single-kernel fusion 3.5x slower — keep dispatches.
// ---------------------------------------------------------------------------
__global__ __launch_bounds__(256, 4) void sage_fused_kernel(
    const int* __restrict__ deg,
    const unsigned short* __restrict__ srcs,
    const uint4* __restrict__ xin4,          // bf16 rows, previous layer
    const unsigned short* __restrict__ xin,  // scalar view of same buffer
    const unsigned short* __restrict__ wpk,  // this layer, B-frag order (kt-major)
    const float* __restrict__ bl,
    const float* __restrict__ g,
    const float* __restrict__ b,
    unsigned short* __restrict__ xh_out,     // bf16 out (non-last layers)
    float* __restrict__ xout)                // fp32 out (last layer), else null
{
    __shared__ unsigned short wlds[8192];       // 16 KB: one kt-pair of W frags
    __shared__ uint4 aggl[64 * 16];             // 16 KB agg tile (swizzled)

    int t    = threadIdx.x;
    int wave = t >> 6;
    int lane = t & 63;
    int cl   = lane & 15;
    int q    = lane >> 4;

    // stage pass-0 weights (kt 0,1); loads stay in flight under gather
    {
        const s16x8* srcv = (const s16x8*)wpk;
        s16x8* dstv = (s16x8*)wlds;
        #pragma unroll
        for (int i = 0; i < 4; ++i) dstv[t + i * 256] = srcv[t + i * 256];
    }

    int m0 = blockIdx.x * 64;

    // ---- gather phase: this wave fills rows [wave*16, wave*16+16) ----
    for (int r = 0; r < 4; ++r) {
        int nl = wave * 16 + r * 4 + q;
        int n  = m0 + nl;
        float acc[8];
        #pragma unroll
        for (int k = 0; k < 8; ++k) acc[k] = 0.f;
        if (n < NNODES) {
            int dg  = deg[n];
            int beg = n * CAP;
            for (int j = 0; j < dg; j += 8) {
                int sidx[8];
                #pragma unroll
                for (int c = 0; c < 8; ++c) {
                    int jj = j + c;
                    sidx[c] = (jj < dg) ? (int)srcs[beg + jj] : -1;
                }
                uint4 u[8];
                #pragma unroll
                for (int c = 0; c < 8; ++c) {
                    u[c] = make_uint4(0u, 0u, 0u, 0u);
                    if (sidx[c] >= 0) u[c] = xin4[(size_t)sidx[c] * 16 + cl];
                }
                #pragma unroll
                for (int c = 0; c < 8; ++c) {
                    acc[0] += bflo(u[c].x); acc[1] += bfhi(u[c].x);
                    acc[2] += bflo(u[c].y); acc[3] += bfhi(u[c].y);
                    acc[4] += bflo(u[c].z); acc[5] += bfhi(u[c].z);
                    acc[6] += bflo(u[c].w); acc[7] += bfhi(u[c].w);
                }
            }
        }
        uint4 o;
        o.x = (u32)f2bf(acc[0]) | ((u32)f2bf(acc[1]) << 16);
        o.y = (u32)f2bf(acc[2]) | ((u32)f2bf(acc[3]) << 16);
        o.z = (u32)f2bf(acc[4]) | ((u32)f2bf(acc[5]) << 16);
        o.w = (u32)f2bf(acc[6]) | ((u32)f2bf(acc[7]) << 16);
        aggl[nl * 16 + (cl ^ (nl & 7))] = o;
    }

    int wbase = m0 + wave * 16;
    int mrow  = wave * 16 + cl;
    int m  = wbase + cl;
    int mc = (m < NNODES) ? m : (NNODES - 1);

    // prefetch xin A-frags (kt 4..7) before the barrier (overlaps barrier wait)
    s16x8 af47[4];
    #pragma unroll
    for (int kt = 4; kt < 8; ++kt)
        af47[kt - 4] = *(const s16x8*)(xin + (size_t)mc * DDIM + (kt - 4) * 32 + q * 8);

    __syncthreads();   // covers pass-0 wlds staging + aggl tile

    f32x4 accm[8];
    #pragma unroll
    for (int ct = 0; ct < 8; ++ct) accm[ct] = (f32x4){0.f, 0.f, 0.f, 0.f};

    #pragma unroll
    for (int p = 0; p < 4; ++p) {
        #pragma unroll
        for (int kk = 0; kk < 2; ++kk) {
            int kt = p * 2 + kk;
            s16x8 af;
            if (kt < 4)
                af = *(const s16x8*)&aggl[mrow * 16 + ((kt * 4 + q) ^ (cl & 7))];
            else
                af = af47[kt - 4];
            #pragma unroll
            for (int ct = 0; ct < 8; ++ct) {
                s16x8 bfr = *(const s16x8*)&wlds[((((kk << 3) + ct) << 6) + lane) * 8];
                accm[ct] = __builtin_amdgcn_mfma_f32_16x16x32_bf16(af, bfr, accm[ct], 0, 0, 0);
            }
        }
        __syncthreads();   // all waves done reading pass p
        if (p < 3) {
            const s16x8* srcv = (const s16x8*)(wpk + (size_t)(p + 1) * 8192);
            s16x8* dstv = (s16x8*)wlds;
            #pragma unroll
            for (int i = 0; i < 4; ++i) dstv[t + i * 256] = srcv[t + i * 256];
            __syncthreads();   // pass p+1 staged
        }
    }

    float bias[8], gg[8], bb[8];
    #pragma unroll
    for (int ct = 0; ct < 8; ++ct) {
        int c = ct * 16 + cl;
        bias[ct] = bl[c]; gg[ct] = g[c]; bb[ct] = b[c];
    }

    float hbuf[8][4];
    #pragma unroll
    for (int ct = 0; ct < 8; ++ct) {
        #pragma unroll
        for (int rr = 0; rr < 4; ++rr) {
            int node = wbase + q * 4 + rr;
            int nc   = (node < NNODES) ? node : (NNODES - 1);
            float hv = fmaxf(accm[ct][rr] + bias[ct], 0.0f);
            hbuf[ct][rr] = hv + bf2f_u(xin[(size_t)nc * DDIM + ct * 16 + cl]);
        }
    }

    float s[4], s2[4];
    #pragma unroll
    for (int rr = 0; rr < 4; ++rr) {
        float a0 = 0.f, a1 = 0.f;
        #pragma unroll
        for (int ct = 0; ct < 8; ++ct) {
            a0 += hbuf[ct][rr];
            a1 += hbuf[ct][rr] * hbuf[ct][rr];
        }
        #pragma unroll
        for (int msk = 1; msk < 16; msk <<= 1) {
            a0 += __shfl_xor(a0, msk, 64);
            a1 += __shfl_xor(a1, msk, 64);
        }
        s[rr] = a0; s2[rr] = a1;
    }

    #pragma unroll
    for (int rr = 0; rr < 4; ++rr) {
        int node = wbase + q * 4 + rr;
        if (node >= NNODES) continue;
        float mean = s[rr] * (1.0f / DDIM);
        float var  = s2[rr] * (1.0f / DDIM) - mean * mean;
        float rstd = rsqrtf(var + LN_EPS);
        #pragma unroll
        for (int ct = 0; ct < 8; ++ct) {
            float y = (hbuf[ct][rr] - mean) * rstd * gg[ct] + bb[ct];
            size_t off = (size_t)node * DDIM + ct * 16 + cl;
            if (xout) xout[off]    = y;          // last layer: fp32 only
            else      xh_out[off]  = f2bf(y);
        }
    }
}

// ---------------------------------------------------------------------------
extern "C" void kernel_launch(void* const* d_in, const int* in_sizes, int n_in,
                              void* d_out, int out_size, void* d_ws, size_t ws_size,
                              hipStream_t stream)
{
    const float* node_emb = (const float*)d_in[0];
    const int*   pos      = (const int*)d_in[1];
    const int*   edge     = (const int*)d_in[2];
    const float* pos_tab  = (const float*)d_in[3];
    const float* Wl       = (const float*)d_in[4];
    const float* bl       = (const float*)d_in[5];
    const float* Wr       = (const float*)d_in[6];
    const float* eg       = (const float*)d_in[7];
    const float* eb       = (const float*)d_in[8];
    const float* hg       = (const float*)d_in[9];
    const float* hb       = (const float*)d_in[10];

    // workspace: [xA bf16 12.8M][xB bf16 12.8M][wpk 0.2M][cursor 0.2M][srcs u16 6.4M]
    unsigned short* xA  = (unsigned short*)d_ws;
    unsigned short* xB  = xA + (size_t)NNODES * DDIM;
    unsigned short* wpk = xB + (size_t)NNODES * DDIM;
    int* cursor = (int*)(wpk + (size_t)NLAYERS * 4096 * 8);
    unsigned short* srcs = (unsigned short*)(cursor + NNODES);

    // ---- cursor zero, then fill/embed interleaved + wpack in ONE dispatch ----
    hipMemsetAsync(cursor, 0, NNODES * sizeof(int), stream);
    prep_kernel<<<PAIRB + WPACKB, 256, 0, stream>>>(
        edge, cursor, srcs, Wl, Wr, wpk,
        node_emb, pos, pos_tab, eg, eb, (uint4*)xA);

    // ---- layers: fused gather+MFMA+LN, ping-pong xA/xB ----
    for (int l = 0; l < NLAYERS; ++l) {
        unsigned short* xin = (l & 1) ? xB : xA;
        unsigned short* xo  = (l & 1) ? xA : xB;
        sage_fused_kernel<<<(NNODES + 63) / 64, 256, 0, stream>>>(
            cursor, srcs, (const uint4*)xin, xin,
            wpk + (size_t)l * 4096 * 8,
            bl + (size_t)l * DDIM,
            hg + (size_t)l * DDIM,
            hb + (size_t)l * DDIM,
            xo, (l == NLAYERS - 1) ? (float*)d_out : (float*)nullptr);
    }
}